// Round 6
// baseline (240.436 us; speedup 1.0000x reference)
//
#include <hip/hip_runtime.h>
#include <hip/hip_bf16.h>

// ---- problem constants ----
#define T_TOK 2048
#define HID   1024
#define FF    1024
#define NEXP  8
#define NPAIR 4096

// ---- GEMM tiling ----
#define BM 128
#define BK 32
#define MAX_MT 40
#define MAXROWS (MAX_MT*BM)   // 5120
#define PPT (NPAIR/256)       // 16

using bf16x8 = __attribute__((ext_vector_type(8))) __bf16;
using f32x4  = __attribute__((ext_vector_type(4))) float;
using us8    = __attribute__((ext_vector_type(8))) unsigned short;

__device__ __forceinline__ unsigned short f2bf(float f) {
    unsigned int u = __float_as_uint(f);
    return (unsigned short)((u + 0x7FFF + ((u >> 16) & 1)) >> 16);   // RNE
}
__device__ __forceinline__ float bf2f(unsigned short s) {
    return __uint_as_float(((unsigned int)s) << 16);
}
__device__ __forceinline__ void gll16(const unsigned short* g, unsigned short* l) {
    __builtin_amdgcn_global_load_lds(
        (const __attribute__((address_space(1))) void*)(const void*)g,
        (__attribute__((address_space(3))) void*)(void*)l, 16, 0, 0);
}
__device__ __forceinline__ ushort4 cvt4(float4 v) {
    ushort4 o; o.x = f2bf(v.x); o.y = f2bf(v.y); o.z = f2bf(v.z); o.w = f2bf(v.w);
    return o;
}
template<int N> __device__ __forceinline__ void wait_vm_lgkm0() {
    if constexpr (N == 0)      asm volatile("s_waitcnt vmcnt(0) lgkmcnt(0)" ::: "memory");
    else if constexpr (N == 2) asm volatile("s_waitcnt vmcnt(2) lgkmcnt(0)" ::: "memory");
    else                       asm volatile("s_waitcnt vmcnt(6) lgkmcnt(0)" ::: "memory");
}

// ---------------- prep: hs fp32->bf16 (256 blocks) + scan (block 256) ----------------
// Weight conversion is gone: both GEMMs consume fp32 weights directly.
__global__ void prep_kernel(const float* __restrict__ hs,
                            const int* __restrict__ ids,
                            int* __restrict__ pair_pos,
                            int* __restrict__ row_tok,
                            int* __restrict__ meta,
                            unsigned short* __restrict__ hs_b) {
    int tid = threadIdx.x;
    int bid = blockIdx.x;
    if (bid < 256) {
        // 8 float4 loads -> 4 ushort8 (16B) stores per thread
        long f4 = (long)bid * 2048 + tid * 2;
        float4 v[8];
#pragma unroll
        for (int k = 0; k < 4; k++) {
            v[2 * k]     = ((const float4*)hs)[f4 + k * 512];
            v[2 * k + 1] = ((const float4*)hs)[f4 + k * 512 + 1];
        }
        long u8i = (long)bid * 1024 + tid;
#pragma unroll
        for (int k = 0; k < 4; k++) {
            ushort4 lo = cvt4(v[2 * k]), hi = cvt4(v[2 * k + 1]);
            us8 o;
            o[0] = lo.x; o[1] = lo.y; o[2] = lo.z; o[3] = lo.w;
            o[4] = hi.x; o[5] = hi.y; o[6] = hi.z; o[7] = hi.w;
            ((us8*)hs_b)[u8i + k * 256] = o;
        }
        return;
    }
    // ---- setup: bucket pairs by expert via prefix scan (no atomics) ----
    __shared__ int S[2][256][NEXP];
    __shared__ int base[NEXP];
    int myc[NEXP];
    int eloc[PPT];
#pragma unroll
    for (int e = 0; e < NEXP; e++) myc[e] = 0;
#pragma unroll
    for (int i = 0; i < PPT; i++) {
        int e = ids[tid * PPT + i];
        eloc[i] = e;
#pragma unroll
        for (int ee = 0; ee < NEXP; ee++) myc[ee] += (e == ee);
    }
#pragma unroll
    for (int e = 0; e < NEXP; e++) S[0][tid][e] = myc[e];
    __syncthreads();
    int src = 0;
    for (int d = 1; d < 256; d <<= 1) {
#pragma unroll
        for (int e = 0; e < NEXP; e++) {
            int v = S[src][tid][e];
            if (tid >= d) v += S[src][tid - d][e];
            S[src ^ 1][tid][e] = v;
        }
        __syncthreads();
        src ^= 1;
    }
    if (tid == 0) {
        int mt = 0;
        for (int e = 0; e < NEXP; e++) {
            meta[e] = mt;
            base[e] = mt * BM;
            mt += (S[src][255][e] + BM - 1) / BM;
        }
        meta[NEXP] = mt;
    }
    for (int i = tid; i < MAXROWS; i += 256) row_tok[i] = -1;
    __syncthreads();
    int off[NEXP];
#pragma unroll
    for (int e = 0; e < NEXP; e++) off[e] = base[e] + S[src][tid][e] - myc[e];
#pragma unroll
    for (int i = 0; i < PPT; i++) {
        int p = tid * PPT + i;
        int e = eloc[i];
        int pos = 0;
#pragma unroll
        for (int ee = 0; ee < NEXP; ee++) if (e == ee) pos = off[ee]++;
        pair_pos[p] = pos;
        row_tok[pos] = p >> 1;
    }
}

// ---------------- grouped GEMM with fused fp32->bf16 B-staging ----------------
// 3-buffer LDS, counted vmcnt. Per K-step (6 VMEM issues: 4 B-reg + 2 A-gll16):
//   W1: vmcnt(6) = everything older than last iter's issues has landed
//       (A(ki) in LDS; B(ki) regs long consumed). lgkmcnt(0) = own ds_writes
//       of Bs[ki%3] (done last iter) visible before barrier.
//   barrier; sched_barrier.
//   I:  issue B-reg loads (ki+2) + A-gll16 (ki+2)  [2 iterations of cover]
//   R:  ds_read fragments of buf ki%3
//   C:  cvt B(ki+1) regs -> bf16, ds_write Bs[(ki+1)%3]  (compiler auto-waits
//       the B(ki+1) register loads -- issued a full iteration ago)
//   M:  16 MFMA
// Reg sets brA/brB statically named, loop unrolled x2 (no runtime reg indexing).
// Hazards: buffer write distance 2 vs read at distance 0, all cross-wave
// orderings protected by the barrier (same argument as round-5 structure).
// EPI==1: A rows indirect via row_tok; B = wgu(fp32) with gate/up de-interleave;
//         epilogue silu(gate)*up -> bf16 act. EPI==2: A = act; plain store.
template<int EPI, int NBY, int BN>
__global__ __launch_bounds__(256)
void gemm_moe(const unsigned short* __restrict__ A,
              const float* __restrict__ B,
              unsigned short* __restrict__ Cbf,
              const int* __restrict__ meta,
              const int* __restrict__ row_tok,
              int K, long Bexp) {
    constexpr int NJ = BN / 32;                    // 16-col MFMA tiles per wave
    constexpr int ACH = (BM * BK) / (8 * 256);     // A 16B-chunks per thread (2)
    constexpr int NBCH = (BN * BK) / (8 * 256);    // B 16B-LDS-chunks per thread (2)
    static_assert(ACH == 2 && NBCH == 2, "vmcnt immediates assume 6 loads/stage");
    __shared__ unsigned short As[3][BM * BK];      // 24 KB
    __shared__ unsigned short Bs[3][BN * BK];      // 24 KB

    int tid = threadIdx.x;
    int L = blockIdx.x;
    int xcd = L & 7;
    int slot = L >> 3;
    constexpr int PER = NBY / 8;
    int by = xcd * PER + (slot % PER);
    int bx = slot / PER;
    if (bx >= meta[NEXP]) return;
    int e = 0;
#pragma unroll
    for (int i = 1; i < NEXP; i++) if (bx >= meta[i]) e = i;

    long m0 = (long)bx * BM;
    int n0 = by * BN;
    const float* Bb = B + (long)e * Bexp;

    int lane = tid & 63, wv = tid >> 6;
    const int r = lane & 15;
    const int q = lane >> 4;
    const int mw = (wv >> 1) * 64, nw = (wv & 1) * (BN / 2);
    const int sw = (q ^ ((r >> 1) & 3)) * 8;

    const unsigned short* ap[ACH];
#pragma unroll
    for (int h = 0; h < ACH; h++) {
        int c = h * 256 + tid;
        int row = c >> 2, cp = c & 3;
        int cc = cp ^ ((row >> 1) & 3);
        long grow;
        if (EPI == 1) {
            int tk = row_tok[m0 + row];
            if (tk < 0) tk = 0;               // pad rows: finite garbage, never read
            grow = tk;
        } else {
            grow = m0 + row;
        }
        ap[h] = A + grow * (long)K + cc * 8;
    }
    const float* bp[NBCH];
#pragma unroll
    for (int h = 0; h < NBCH; h++) {
        int c = h * 256 + tid;
        int row = c >> 2, cp = c & 3;
        int cc = cp ^ ((row >> 1) & 3);
        long grow;
        if (EPI == 1) grow = ((row & 1) ? FF : 0) + ((n0 + row) >> 1);
        else          grow = n0 + row;
        bp[h] = Bb + grow * (long)K + cc * 8;
    }

    f32x4 acc[4][NJ] = {};
    const int NKI = K / BK;   // 32 (even)
    float4 brA[2 * NBCH], brB[2 * NBCH];   // B(even k) / B(odd k) reg sets

#define BLOADS(SET, K0) \
    _Pragma("unroll") for (int h = 0; h < NBCH; h++) { \
        SET[2*h]   = *(const float4*)(bp[h] + (K0)); \
        SET[2*h+1] = *(const float4*)(bp[h] + (K0) + 4); }
#define BWRITE(SET, SBUF) \
    _Pragma("unroll") for (int h = 0; h < NBCH; h++) { \
        us8 o_; \
        o_[0]=f2bf(SET[2*h].x);   o_[1]=f2bf(SET[2*h].y); \
        o_[2]=f2bf(SET[2*h].z);   o_[3]=f2bf(SET[2*h].w); \
        o_[4]=f2bf(SET[2*h+1].x); o_[5]=f2bf(SET[2*h+1].y); \
        o_[6]=f2bf(SET[2*h+1].z); o_[7]=f2bf(SET[2*h+1].w); \
        *(us8*)&Bs[SBUF][(h * 256 + tid) * 8] = o_; }
#define AGLL(SBUF, K0) \
    _Pragma("unroll") for (int h = 0; h < ACH; h++) \
        gll16(ap[h] + (K0), &As[SBUF][(h * 256 + tid) * 8]);
#define BODY(KI, LD, CV, VM) do { \
    wait_vm_lgkm0<VM>(); \
    __builtin_amdgcn_s_barrier(); \
    __builtin_amdgcn_sched_barrier(0); \
    int sb_ = (KI) % 3; \
    if ((KI) + 2 < NKI) { \
        int sn_ = ((KI) + 2) % 3; \
        BLOADS(LD, ((KI) + 2) * BK); \
        AGLL(sn_, ((KI) + 2) * BK); \
    } \
    bf16x8 a_[4], b_[NJ]; \
    _Pragma("unroll") for (int i = 0; i < 4; i++) \
        a_[i] = *(const bf16x8*)&As[sb_][(mw + i * 16 + r) * BK + sw]; \
    _Pragma("unroll") for (int j = 0; j < NJ; j++) \
        b_[j] = *(const bf16x8*)&Bs[sb_][(nw + j * 16 + r) * BK + sw]; \
    if ((KI) + 1 < NKI) { int sw_ = ((KI) + 1) % 3; BWRITE(CV, sw_); } \
    _Pragma("unroll") for (int i = 0; i < 4; i++) \
    _Pragma("unroll") for (int j = 0; j < NJ; j++) \
        acc[i][j] = __builtin_amdgcn_mfma_f32_16x16x32_bf16(a_[i], b_[j], acc[i][j], 0, 0, 0); \
} while (0)

    // prologue: B(0)->brA, B(1)->brB, A(0)->As[0], A(1)->As[1]; cvt B(0)->Bs[0]
    BLOADS(brA, 0);
    BLOADS(brB, BK);
    AGLL(0, 0);
    AGLL(1, BK);
    BWRITE(brA, 0);           // compiler auto-waits the brA loads

    BODY(0, brA, brB, 0);     // full drain once; I: B(2)->brA; C: B(1)->Bs[1]
    BODY(1, brB, brA, 6);     //                  I: B(3)->brB; C: B(2)->Bs[2]
    for (int ki = 2; ki < NKI - 2; ki += 2) {
        BODY(ki,     brA, brB, 6);
        BODY(ki + 1, brB, brA, 6);
    }
    BODY(NKI - 2, brA, brB, 6);   // I skipped; C: B(NKI-1)
    BODY(NKI - 1, brB, brA, 0);   // I skipped; C skipped
#undef BODY
#undef AGLL
#undef BWRITE
#undef BLOADS

    // D layout: row = q*4 + reg, col = lane&15 within each 16x16 tile
    if (EPI == 1) {
#pragma unroll
        for (int i = 0; i < 4; i++) {
            long rowb = m0 + mw + i * 16 + q * 4;
#pragma unroll
            for (int j = 0; j < NJ; j++) {
                int n = n0 + nw + j * 16 + r;
#pragma unroll
                for (int reg = 0; reg < 4; reg++) {
                    float v = acc[i][j][reg];
                    float o = __shfl_xor(v, 1);
                    if (!(r & 1)) {
                        float g = v, u = o;
                        float s2 = g / (1.f + __expf(-g)) * u;
                        Cbf[(rowb + reg) * (long)FF + (n >> 1)] = f2bf(s2);
                    }
                }
            }
        }
    } else {
#pragma unroll
        for (int i = 0; i < 4; i++) {
            long rowb = m0 + mw + i * 16 + q * 4;
#pragma unroll
            for (int j = 0; j < NJ; j++) {
                int n = n0 + nw + j * 16 + r;
#pragma unroll
                for (int reg = 0; reg < 4; reg++)
                    Cbf[(rowb + reg) * (long)HID + n] = f2bf(acc[i][j][reg]);
            }
        }
    }
}

// ---------------- weighted combine ----------------
__global__ void combine_kernel(const unsigned short* __restrict__ y,
                               const float* __restrict__ tw,
                               const int* __restrict__ pair_pos,
                               float* __restrict__ out) {
    int t = blockIdx.x;
    int c = threadIdx.x * 4;
    int p0 = pair_pos[t * 2], p1 = pair_pos[t * 2 + 1];
    float w0 = tw[t * 2], w1 = tw[t * 2 + 1];
    ushort4 a = *(const ushort4*)(y + (long)p0 * HID + c);
    ushort4 b = *(const ushort4*)(y + (long)p1 * HID + c);
    float4 o;
    o.x = w0 * bf2f(a.x) + w1 * bf2f(b.x);
    o.y = w0 * bf2f(a.y) + w1 * bf2f(b.y);
    o.z = w0 * bf2f(a.z) + w1 * bf2f(b.z);
    o.w = w0 * bf2f(a.w) + w1 * bf2f(b.w);
    *(float4*)(out + (long)t * HID + c) = o;
}

extern "C" void kernel_launch(void* const* d_in, const int* in_sizes, int n_in,
                              void* d_out, int out_size, void* d_ws, size_t ws_size,
                              hipStream_t stream) {
    const float* hs  = (const float*)d_in[0];
    const float* tw  = (const float*)d_in[1];
    const int*   ids = (const int*)d_in[2];
    const float* wgu = (const float*)d_in[3];
    const float* wdn = (const float*)d_in[4];
    float* out = (float*)d_out;

    char* ws = (char*)d_ws;
    size_t off = 0;
    auto alloc = [&](size_t bytes) -> void* {
        void* p = ws + off;
        off += (bytes + 255) & ~(size_t)255;
        return p;
    };
    unsigned short* hs_b  = (unsigned short*)alloc((size_t)T_TOK * HID * 2);    // 4 MB
    unsigned short* act   = (unsigned short*)alloc((size_t)MAXROWS * FF * 2);   // 10 MB
    unsigned short* ybuf  = (unsigned short*)alloc((size_t)MAXROWS * HID * 2);  // 10 MB
    int* pair_pos = (int*)alloc(NPAIR * 4);
    int* row_tok  = (int*)alloc(MAXROWS * 4);
    int* meta     = (int*)alloc(64);

    prep_kernel<<<257, 256, 0, stream>>>(hs, ids, pair_pos, row_tok, meta, hs_b);

    // GEMM1: (rows x 1024) x wgu_e(2048 x 1024)^T -> silu-fused -> act (bf16)
    gemm_moe<1, 16, 128><<<16 * MAX_MT, 256, 0, stream>>>(
        hs_b, wgu, act, meta, row_tok, HID, (long)(2 * FF) * HID);

    // GEMM2: (rows x 1024) x wdn_e(1024 x 1024)^T -> ybuf (bf16)
    gemm_moe<2, 8, 128><<<8 * MAX_MT, 256, 0, stream>>>(
        act, wdn, ybuf, meta, row_tok, FF, (long)HID * FF);

    combine_kernel<<<T_TOK, 256, 0, stream>>>(ybuf, tw, pair_pos, out);
}

// Round 7
// 219.444 us; speedup vs baseline: 1.0957x; 1.0957x over previous
//
#include <hip/hip_runtime.h>
#include <hip/hip_bf16.h>

// ---- problem constants ----
#define T_TOK 2048
#define HID   1024
#define FF    1024
#define NEXP  8
#define NPAIR 4096

// ---- GEMM tiling ----
#define BM 128
#define BK 32
#define MAX_MT 40
#define MAXROWS (MAX_MT*BM)   // 5120
#define PPT (NPAIR/256)       // 16

using bf16x8 = __attribute__((ext_vector_type(8))) __bf16;
using f32x4  = __attribute__((ext_vector_type(4))) float;
using us8    = __attribute__((ext_vector_type(8))) unsigned short;

__device__ __forceinline__ unsigned short f2bf(float f) {
    unsigned int u = __float_as_uint(f);
    return (unsigned short)((u + 0x7FFF + ((u >> 16) & 1)) >> 16);   // RNE
}
__device__ __forceinline__ float bf2f(unsigned short s) {
    return __uint_as_float(((unsigned int)s) << 16);
}
__device__ __forceinline__ void gll16(const unsigned short* g, unsigned short* l) {
    __builtin_amdgcn_global_load_lds(
        (const __attribute__((address_space(1))) void*)(const void*)g,
        (__attribute__((address_space(3))) void*)(void*)l, 16, 0, 0);
}
__device__ __forceinline__ ushort4 cvt4(float4 v) {
    ushort4 o; o.x = f2bf(v.x); o.y = f2bf(v.y); o.z = f2bf(v.z); o.w = f2bf(v.w);
    return o;
}

// ---------------- prep: loop-free streaming convert (16B stores) + scan ----------------
//   [0,2048)      : wgu  (4.19M float4)   8 f32x4 loads -> 4 us8 stores / thread
//   [2048,3072)   : wdn  (2.10M float4)
//   [3072,3328)   : hs   (0.52M float4)
//   3328          : expert-bucket prefix scan
#define B_WGU 2048
#define B_WDN 1024
#define B_HS  256
#define B_TOT (B_WGU + B_WDN + B_HS)   // 3328

__global__ void prep_kernel(const float* __restrict__ wgu,
                            const float* __restrict__ wdn,
                            const float* __restrict__ hs,
                            const int* __restrict__ ids,
                            int* __restrict__ pair_pos,
                            int* __restrict__ row_tok,
                            int* __restrict__ meta,
                            unsigned short* __restrict__ wgu_b,
                            unsigned short* __restrict__ wdn_b,
                            unsigned short* __restrict__ hs_b) {
    int tid = threadIdx.x;
    int bid = blockIdx.x;
    if (bid < B_TOT) {
        const float4* src;
        us8* dst;
        long rel;
        if (bid < B_WGU)            { src = (const float4*)wgu; dst = (us8*)wgu_b; rel = bid; }
        else if (bid < B_WGU+B_WDN) { src = (const float4*)wdn; dst = (us8*)wdn_b; rel = bid - B_WGU; }
        else                        { src = (const float4*)hs;  dst = (us8*)hs_b;  rel = bid - B_WGU - B_WDN; }
        long f4 = rel * 2048 + tid * 2;
        float4 v[8];
#pragma unroll
        for (int k = 0; k < 4; k++) {
            v[2 * k]     = src[f4 + k * 512];
            v[2 * k + 1] = src[f4 + k * 512 + 1];
        }
        long u8i = rel * 1024 + tid;
#pragma unroll
        for (int k = 0; k < 4; k++) {
            ushort4 lo = cvt4(v[2 * k]), hi = cvt4(v[2 * k + 1]);
            us8 o;
            o[0] = lo.x; o[1] = lo.y; o[2] = lo.z; o[3] = lo.w;
            o[4] = hi.x; o[5] = hi.y; o[6] = hi.z; o[7] = hi.w;
            dst[u8i + k * 256] = o;
        }
        return;
    }
    // ---- setup: bucket pairs by expert via prefix scan (no atomics) ----
    __shared__ int S[2][256][NEXP];
    __shared__ int base[NEXP];
    int myc[NEXP];
    int eloc[PPT];
#pragma unroll
    for (int e = 0; e < NEXP; e++) myc[e] = 0;
#pragma unroll
    for (int i = 0; i < PPT; i++) {
        int e = ids[tid * PPT + i];
        eloc[i] = e;
#pragma unroll
        for (int ee = 0; ee < NEXP; ee++) myc[ee] += (e == ee);
    }
#pragma unroll
    for (int e = 0; e < NEXP; e++) S[0][tid][e] = myc[e];
    __syncthreads();
    int src = 0;
    for (int d = 1; d < 256; d <<= 1) {
#pragma unroll
        for (int e = 0; e < NEXP; e++) {
            int v = S[src][tid][e];
            if (tid >= d) v += S[src][tid - d][e];
            S[src ^ 1][tid][e] = v;
        }
        __syncthreads();
        src ^= 1;
    }
    if (tid == 0) {
        int mt = 0;
        for (int e = 0; e < NEXP; e++) {
            meta[e] = mt;
            base[e] = mt * BM;
            mt += (S[src][255][e] + BM - 1) / BM;
        }
        meta[NEXP] = mt;
    }
    for (int i = tid; i < MAXROWS; i += 256) row_tok[i] = -1;
    __syncthreads();
    int off[NEXP];
#pragma unroll
    for (int e = 0; e < NEXP; e++) off[e] = base[e] + S[src][tid][e] - myc[e];
#pragma unroll
    for (int i = 0; i < PPT; i++) {
        int p = tid * PPT + i;
        int e = eloc[i];
        int pos = 0;
#pragma unroll
        for (int ee = 0; ee < NEXP; ee++) if (e == ee) pos = off[ee]++;
        pair_pos[p] = pos;
        row_tok[pos] = p >> 1;
    }
}

// ---------------- grouped GEMM: intra-block split-K, 8 waves / 512 threads ----------------
// Two 4-wave teams per block. Team h computes the SAME 128xBN output tile over
// K-half h with its own double-buffered LDS pipeline (exact R1 2-barrier
// schedule, block-wide barriers, symmetric across teams). Cross-team f32
// reduction through LDS at the end, then the usual epilogue on team 0.
// Why: grid is small (576/640 blocks); 4-wave blocks give only ~9 waves/CU
// (latency basin, MfmaUtil 16%). 8-wave blocks at the same grid double the
// resident waves (~16-18/CU) without shrinking per-wave MFMA work.
// EPI==1: A rows indirect via row_tok (clamped); B = wgu_b with gate/up
//         de-interleave in staging; epilogue silu(gate)*up -> bf16 act (FF cols).
// EPI==2: A = act (bucket-ordered, direct); epilogue plain bf16 store to ybuf.
template<int EPI, int NBY, int BN>
__global__ __launch_bounds__(512)
void gemm_moe(const unsigned short* __restrict__ A,
              const unsigned short* __restrict__ B,
              unsigned short* __restrict__ Cbf,
              const int* __restrict__ meta,
              const int* __restrict__ row_tok,
              int K, long Bexp) {
    constexpr int BN2 = BN / 2;                    // per-wave n-width
    constexpr int NJ  = BN / 32;                   // 16-col MFMA tiles per wave
    constexpr int ACH = (BM * BK) / (8 * 256);     // A 16B-chunks per team-thread (2)
    constexpr int BCH = (BN * BK) / (8 * 256);     // B 16B-chunks per team-thread (2 or 1)
    constexpr int ABYTES = 2 * 2 * BM * BK * 2;    // 32 KB  [buf][team]
    constexpr int BBYTES = 2 * 2 * BN * BK * 2;    // 32/16 KB
    __shared__ __align__(16) unsigned char smem[ABYTES + BBYTES];  // 64/48 KB
    unsigned short* Asm = (unsigned short*)smem;
    unsigned short* Bsm = (unsigned short*)(smem + ABYTES);

    int tid = threadIdx.x;
    int L = blockIdx.x;
    // XCD-locality decode: xcd = L%8 gets NBY/8 consecutive by-slabs for ALL bx
    int xcd = L & 7;
    int slot = L >> 3;
    constexpr int PER = NBY / 8;
    int by = xcd * PER + (slot % PER);
    int bx = slot / PER;
    if (bx >= meta[NEXP]) return;
    int e = 0;
#pragma unroll
    for (int i = 1; i < NEXP; i++) if (bx >= meta[i]) e = i;

    long m0 = (long)bx * BM;
    int n0 = by * BN;
    const unsigned short* Bb = B + (long)e * Bexp;

    int lane = tid & 63, wv = tid >> 6;
    int team = wv >> 2, wq = wv & 3;               // K-half team, quad within team
    int t256 = tid & 255;                          // thread id within team
    const int r = lane & 15;
    const int q = lane >> 4;
    const int mw = (wq >> 1) * 64, nw = (wq & 1) * BN2;
    const int sw = (q ^ ((r >> 1) & 3)) * 8;
    const int kbase = team * (K / 2);

    // per-thread staging pointers for this team's buffers (rows fixed across K)
    const unsigned short* ap[ACH];
#pragma unroll
    for (int h = 0; h < ACH; h++) {
        int c = h * 256 + t256;
        int row = c >> 2, cp = c & 3;
        int cc = cp ^ ((row >> 1) & 3);
        long grow;
        if (EPI == 1) {
            int tk = row_tok[m0 + row];
            if (tk < 0) tk = 0;               // pad rows: finite garbage, never read
            grow = tk;
        } else {
            grow = m0 + row;
        }
        ap[h] = A + grow * (long)K + kbase + cc * 8;
    }
    const unsigned short* bp[BCH];
#pragma unroll
    for (int h = 0; h < BCH; h++) {
        int c = h * 256 + t256;
        int row = c >> 2, cp = c & 3;
        int cc = cp ^ ((row >> 1) & 3);
        long grow;
        if (EPI == 1) grow = ((row & 1) ? FF : 0) + ((n0 + row) >> 1);
        else          grow = n0 + row;
        bp[h] = Bb + grow * (long)K + kbase + cc * 8;
    }

    auto AS = [&](int s) { return Asm + (s * 2 + team) * (BM * BK); };
    auto BS = [&](int s) { return Bsm + (s * 2 + team) * (BN * BK); };
    auto stage = [&](int s, int k0) {
#pragma unroll
        for (int h = 0; h < ACH; h++)
            gll16(ap[h] + k0, &AS(s)[(h * 256 + t256) * 8]);
#pragma unroll
        for (int h = 0; h < BCH; h++)
            gll16(bp[h] + k0, &BS(s)[(h * 256 + t256) * 8]);
    };

    f32x4 acc[4][NJ] = {};
    const int NKI = K / (2 * BK);   // 16 per team
    stage(0, 0);
    for (int ki = 0; ki < NKI; ki++) {
        __syncthreads();      // own stage(ki) drained (vmcnt0 before barrier)
        if (ki + 1 < NKI) stage((ki + 1) & 1, (ki + 1) * BK);
        int s = ki & 1;
        const unsigned short* as_ = AS(s);
        const unsigned short* bs_ = BS(s);
        bf16x8 a[4], b[NJ];
#pragma unroll
        for (int i = 0; i < 4; i++)
            a[i] = *(const bf16x8*)&as_[(mw + i * 16 + r) * BK + sw];
#pragma unroll
        for (int j = 0; j < NJ; j++)
            b[j] = *(const bf16x8*)&bs_[(nw + j * 16 + r) * BK + sw];
#pragma unroll
        for (int i = 0; i < 4; i++)
#pragma unroll
            for (int j = 0; j < NJ; j++)
                acc[i][j] = __builtin_amdgcn_mfma_f32_16x16x32_bf16(a[i], b[j], acc[i][j], 0, 0, 0);
        __syncthreads();      // all reads of buf[s] done before next overwrite cycle
    }

    // ---- cross-team reduction through LDS (staging buffers are dead now) ----
    // region per quad: 64 x BN2 f32. G1: 4*64*64*4 = 64 KB (= smem). G2: 32 KB.
    float* red = (float*)smem;
    float* wr = red + wq * (64 * BN2);
    if (team == 1) {
#pragma unroll
        for (int i = 0; i < 4; i++)
#pragma unroll
            for (int j = 0; j < NJ; j++)
#pragma unroll
                for (int reg = 0; reg < 4; reg++)
                    wr[(i * 16 + q * 4 + reg) * BN2 + j * 16 + r] = acc[i][j][reg];
    }
    __syncthreads();
    if (team == 1) return;
#pragma unroll
    for (int i = 0; i < 4; i++)
#pragma unroll
        for (int j = 0; j < NJ; j++)
#pragma unroll
            for (int reg = 0; reg < 4; reg++)
                acc[i][j][reg] += wr[(i * 16 + q * 4 + reg) * BN2 + j * 16 + r];

    // D layout: row = q*4 + reg, col = lane&15 within each 16x16 tile
    if (EPI == 1) {
#pragma unroll
        for (int i = 0; i < 4; i++) {
            long rowb = m0 + mw + i * 16 + q * 4;
#pragma unroll
            for (int j = 0; j < NJ; j++) {
                int n = n0 + nw + j * 16 + r;
#pragma unroll
                for (int reg = 0; reg < 4; reg++) {
                    float v = acc[i][j][reg];
                    float o = __shfl_xor(v, 1);
                    if (!(r & 1)) {
                        float g = v, u = o;
                        float s2 = g / (1.f + __expf(-g)) * u;
                        Cbf[(rowb + reg) * (long)FF + (n >> 1)] = f2bf(s2);
                    }
                }
            }
        }
    } else {
#pragma unroll
        for (int i = 0; i < 4; i++) {
            long rowb = m0 + mw + i * 16 + q * 4;
#pragma unroll
            for (int j = 0; j < NJ; j++) {
                int n = n0 + nw + j * 16 + r;
#pragma unroll
                for (int reg = 0; reg < 4; reg++)
                    Cbf[(rowb + reg) * (long)HID + n] = f2bf(acc[i][j][reg]);
            }
        }
    }
}

// ---------------- weighted combine ----------------
__global__ void combine_kernel(const unsigned short* __restrict__ y,
                               const float* __restrict__ tw,
                               const int* __restrict__ pair_pos,
                               float* __restrict__ out) {
    int t = blockIdx.x;
    int c = threadIdx.x * 4;
    int p0 = pair_pos[t * 2], p1 = pair_pos[t * 2 + 1];
    float w0 = tw[t * 2], w1 = tw[t * 2 + 1];
    ushort4 a = *(const ushort4*)(y + (long)p0 * HID + c);
    ushort4 b = *(const ushort4*)(y + (long)p1 * HID + c);
    float4 o;
    o.x = w0 * bf2f(a.x) + w1 * bf2f(b.x);
    o.y = w0 * bf2f(a.y) + w1 * bf2f(b.y);
    o.z = w0 * bf2f(a.z) + w1 * bf2f(b.z);
    o.w = w0 * bf2f(a.w) + w1 * bf2f(b.w);
    *(float4*)(out + (long)t * HID + c) = o;
}

extern "C" void kernel_launch(void* const* d_in, const int* in_sizes, int n_in,
                              void* d_out, int out_size, void* d_ws, size_t ws_size,
                              hipStream_t stream) {
    const float* hs  = (const float*)d_in[0];
    const float* tw  = (const float*)d_in[1];
    const int*   ids = (const int*)d_in[2];
    const float* wgu = (const float*)d_in[3];
    const float* wdn = (const float*)d_in[4];
    float* out = (float*)d_out;

    char* ws = (char*)d_ws;
    size_t off = 0;
    auto alloc = [&](size_t bytes) -> void* {
        void* p = ws + off;
        off += (bytes + 255) & ~(size_t)255;
        return p;
    };
    unsigned short* wgu_b = (unsigned short*)alloc((size_t)NEXP * 2 * FF * HID * 2); // 32 MB
    unsigned short* wdn_b = (unsigned short*)alloc((size_t)NEXP * HID * FF * 2);     // 16 MB
    unsigned short* hs_b  = (unsigned short*)alloc((size_t)T_TOK * HID * 2);         // 4 MB
    unsigned short* act   = (unsigned short*)alloc((size_t)MAXROWS * FF * 2);        // 10 MB
    unsigned short* ybuf  = (unsigned short*)alloc((size_t)MAXROWS * HID * 2);       // 10 MB
    int* pair_pos = (int*)alloc(NPAIR * 4);
    int* row_tok  = (int*)alloc(MAXROWS * 4);
    int* meta     = (int*)alloc(64);

    prep_kernel<<<B_TOT + 1, 256, 0, stream>>>(wgu, wdn, hs, ids,
                                               pair_pos, row_tok, meta,
                                               wgu_b, wdn_b, hs_b);

    // GEMM1: (rows x 1024) x B_e(2048 x 1024)^T -> fused silu -> act (rows x 1024)
    // 512-thr blocks, split-K teams; grid 16 by * 40 bx
    gemm_moe<1, 16, 128><<<16 * MAX_MT, 512, 0, stream>>>(
        hs_b, wgu_b, act, meta, row_tok, HID, (long)(2 * FF) * HID);

    // GEMM2: (rows x 1024) x B_e(1024 x 1024)^T -> ybuf (rows x 1024) bf16
    // BN=64 -> 16 by-tiles -> grid 640, 48 KB LDS -> 3 blocks/CU capacity
    gemm_moe<2, 16, 64><<<16 * MAX_MT, 512, 0, stream>>>(
        act, wdn_b, ybuf, meta, row_tok, FF, (long)HID * FF);

    combine_kernel<<<T_TOK, 256, 0, stream>>>(ybuf, tw, pair_pos, out);
}

// Round 8
// 218.347 us; speedup vs baseline: 1.1012x; 1.0050x over previous
//
#include <hip/hip_runtime.h>
#include <hip/hip_bf16.h>

// ---- problem constants ----
#define T_TOK 2048
#define HID   1024
#define FF    1024
#define NEXP  8
#define NPAIR 4096

// ---- GEMM tiling ----
#define BM 128
#define BK 32
#define MAX_MT 40
#define MAXROWS (MAX_MT*BM)   // 5120
#define PPT (NPAIR/256)       // 16

using bf16x8 = __attribute__((ext_vector_type(8))) __bf16;
using f32x4  = __attribute__((ext_vector_type(4))) float;
using us8    = __attribute__((ext_vector_type(8))) unsigned short;

__device__ __forceinline__ unsigned short f2bf(float f) {
    unsigned int u = __float_as_uint(f);
    return (unsigned short)((u + 0x7FFF + ((u >> 16) & 1)) >> 16);   // RNE
}
__device__ __forceinline__ float bf2f(unsigned short s) {
    return __uint_as_float(((unsigned int)s) << 16);
}
__device__ __forceinline__ void gll16(const unsigned short* g, unsigned short* l) {
    __builtin_amdgcn_global_load_lds(
        (const __attribute__((address_space(1))) void*)(const void*)g,
        (__attribute__((address_space(3))) void*)(void*)l, 16, 0, 0);
}
__device__ __forceinline__ void gll16f(const float* g, float* l) {
    __builtin_amdgcn_global_load_lds(
        (const __attribute__((address_space(1))) void*)(const void*)g,
        (__attribute__((address_space(3))) void*)(void*)l, 16, 0, 0);
}
__device__ __forceinline__ ushort4 cvt4(float4 v) {
    ushort4 o; o.x = f2bf(v.x); o.y = f2bf(v.y); o.z = f2bf(v.z); o.w = f2bf(v.w);
    return o;
}

// ---------------- prep: hs fp32->bf16 (256 blocks) + scan (block 256) ----------------
// Weight conversion eliminated: GEMMs stage fp32 weights directly to LDS and
// convert during the fragment read (RNE, numerically identical).
__global__ void prep_kernel(const float* __restrict__ hs,
                            const int* __restrict__ ids,
                            int* __restrict__ pair_pos,
                            int* __restrict__ row_tok,
                            int* __restrict__ meta,
                            unsigned short* __restrict__ hs_b) {
    int tid = threadIdx.x;
    int bid = blockIdx.x;
    if (bid < 256) {
        long f4 = (long)bid * 2048 + tid * 2;
        float4 v[8];
#pragma unroll
        for (int k = 0; k < 4; k++) {
            v[2 * k]     = ((const float4*)hs)[f4 + k * 512];
            v[2 * k + 1] = ((const float4*)hs)[f4 + k * 512 + 1];
        }
        long u8i = (long)bid * 1024 + tid;
#pragma unroll
        for (int k = 0; k < 4; k++) {
            ushort4 lo = cvt4(v[2 * k]), hi = cvt4(v[2 * k + 1]);
            us8 o;
            o[0] = lo.x; o[1] = lo.y; o[2] = lo.z; o[3] = lo.w;
            o[4] = hi.x; o[5] = hi.y; o[6] = hi.z; o[7] = hi.w;
            ((us8*)hs_b)[u8i + k * 256] = o;
        }
        return;
    }
    // ---- setup: bucket pairs by expert via prefix scan (no atomics) ----
    __shared__ int S[2][256][NEXP];
    __shared__ int base[NEXP];
    int myc[NEXP];
    int eloc[PPT];
#pragma unroll
    for (int e = 0; e < NEXP; e++) myc[e] = 0;
#pragma unroll
    for (int i = 0; i < PPT; i++) {
        int e = ids[tid * PPT + i];
        eloc[i] = e;
#pragma unroll
        for (int ee = 0; ee < NEXP; ee++) myc[ee] += (e == ee);
    }
#pragma unroll
    for (int e = 0; e < NEXP; e++) S[0][tid][e] = myc[e];
    __syncthreads();
    int src = 0;
    for (int d = 1; d < 256; d <<= 1) {
#pragma unroll
        for (int e = 0; e < NEXP; e++) {
            int v = S[src][tid][e];
            if (tid >= d) v += S[src][tid - d][e];
            S[src ^ 1][tid][e] = v;
        }
        __syncthreads();
        src ^= 1;
    }
    if (tid == 0) {
        int mt = 0;
        for (int e = 0; e < NEXP; e++) {
            meta[e] = mt;
            base[e] = mt * BM;
            mt += (S[src][255][e] + BM - 1) / BM;
        }
        meta[NEXP] = mt;
    }
    for (int i = tid; i < MAXROWS; i += 256) row_tok[i] = -1;
    __syncthreads();
    int off[NEXP];
#pragma unroll
    for (int e = 0; e < NEXP; e++) off[e] = base[e] + S[src][tid][e] - myc[e];
#pragma unroll
    for (int i = 0; i < PPT; i++) {
        int p = tid * PPT + i;
        int e = eloc[i];
        int pos = 0;
#pragma unroll
        for (int ee = 0; ee < NEXP; ee++) if (e == ee) pos = off[ee]++;
        pair_pos[p] = pos;
        row_tok[pos] = p >> 1;
    }
}

// ---------------- grouped GEMM: A bf16 / B fp32 staged, cvt at fragment read ----------------
// R1's exact 2-barrier double-buffer pipeline. B is staged as RAW fp32 via
// global_load_lds (no reg roundtrip, no ds_write -- the R2/R6 failure modes),
// and converted fp32->bf16 (RNE casts -> v_cvt_pk_bf16_f32) during the
// LDS->fragment read, off the barrier path.
// B LDS layout: [BN][32] floats, 8x16B chunks/row; chunk at LDS position p of
// row R holds logical chunk p^(R&7) (bank-decorrelates the 128B rows). LDS dest
// stays LINEAR (gll16 requirement); the XOR is applied to the GLOBAL source
// chunk (rule: pre-swizzled source + matching swizzled read). Per-16-lane read
// phase: bank-group (2q)^(r&7) -> 2 lanes/4-bank group = conflict-free.
// EPI==1: A rows indirect via row_tok (clamped); B = wgu(fp32) with gate/up
//         de-interleave in staging; epilogue silu(gate)*up -> bf16 act (FF cols).
// EPI==2: A = act (bucket-ordered, direct); epilogue plain bf16 store to ybuf.
template<int EPI, int NBY, int BN>
__global__ __launch_bounds__(256)
void gemm_moe(const unsigned short* __restrict__ A,
              const float* __restrict__ B,
              unsigned short* __restrict__ Cbf,
              const int* __restrict__ meta,
              const int* __restrict__ row_tok,
              int K, long Bexp) {
    constexpr int NJ = BN / 32;                    // 16-col MFMA tiles per wave
    constexpr int ACH = (BM * BK) / (8 * 256);     // A 16B-chunks per thread (2)
    constexpr int BCH = (BN * 8) / 256;            // B 16B-chunks per thread (4)
    __shared__ unsigned short As[2][BM * BK];      // 16 KB
    __shared__ float          BsF[2][BN * BK];     // 32 KB fp32

    int tid = threadIdx.x;
    int L = blockIdx.x;
    // XCD-locality decode: xcd = L%8 gets NBY/8 consecutive by-slabs for ALL bx
    int xcd = L & 7;
    int slot = L >> 3;
    constexpr int PER = NBY / 8;
    int by = xcd * PER + (slot % PER);
    int bx = slot / PER;
    if (bx >= meta[NEXP]) return;
    int e = 0;
#pragma unroll
    for (int i = 1; i < NEXP; i++) if (bx >= meta[i]) e = i;

    long m0 = (long)bx * BM;
    int n0 = by * BN;
    const float* Bb = B + (long)e * Bexp;

    int lane = tid & 63, wv = tid >> 6;
    const int r = lane & 15;
    const int q = lane >> 4;
    const int mw = (wv >> 1) * 64, nw = (wv & 1) * (BN / 2);
    const int sw = (q ^ ((r >> 1) & 3)) * 8;       // A swizzle (bf16, 64B rows)

    // A staging pointers (bf16, unchanged layout)
    const unsigned short* ap[ACH];
#pragma unroll
    for (int h = 0; h < ACH; h++) {
        int c = h * 256 + tid;
        int row = c >> 2, cp = c & 3;
        int cc = cp ^ ((row >> 1) & 3);
        long grow;
        if (EPI == 1) {
            int tk = row_tok[m0 + row];
            if (tk < 0) tk = 0;               // pad rows: finite garbage, never read
            grow = tk;
        } else {
            grow = m0 + row;
        }
        ap[h] = A + grow * (long)K + cc * 8;
    }
    // B staging pointers (fp32): LDS chunk c=h*256+tid (linear dest) sources
    // global chunk (c&7)^(row&7) of row c>>3.
    const float* bp[BCH];
#pragma unroll
    for (int h = 0; h < BCH; h++) {
        int c = h * 256 + tid;
        int row = c >> 3, pos = c & 7;
        int srcc = pos ^ (row & 7);
        long grow;
        if (EPI == 1) grow = ((row & 1) ? FF : 0) + ((n0 + row) >> 1);
        else          grow = n0 + row;
        bp[h] = Bb + grow * (long)K + srcc * 4;
    }

    auto stage = [&](int s, int k0) {
#pragma unroll
        for (int h = 0; h < ACH; h++)
            gll16(ap[h] + k0, &As[s][(h * 256 + tid) * 8]);
#pragma unroll
        for (int h = 0; h < BCH; h++)
            gll16f(bp[h] + k0, &BsF[s][(h * 256 + tid) * 4]);
    };

    f32x4 acc[4][NJ] = {};
    const int NKI = K / BK;   // 32
    stage(0, 0);
    for (int ki = 0; ki < NKI; ki++) {
        __syncthreads();      // buf[ki&1] loads landed; buf[(ki+1)&1] free to overwrite
        if (ki + 1 < NKI) stage((ki + 1) & 1, (ki + 1) * BK);
        int s = ki & 1;
        bf16x8 a[4], b[NJ];
#pragma unroll
        for (int i = 0; i < 4; i++)
            a[i] = *(const bf16x8*)&As[s][(mw + i * 16 + r) * BK + sw];
#pragma unroll
        for (int j = 0; j < NJ; j++) {
            int R = nw + j * 16 + r;
            int m = R & 7;
            const float* bs_ = &BsF[s][R * 32];
            f32x4 lo = *(const f32x4*)&bs_[((2 * q) ^ m) << 2];
            f32x4 hi = *(const f32x4*)&bs_[((2 * q + 1) ^ m) << 2];
            bf16x8 bb;
            bb[0] = (__bf16)lo[0]; bb[1] = (__bf16)lo[1];
            bb[2] = (__bf16)lo[2]; bb[3] = (__bf16)lo[3];
            bb[4] = (__bf16)hi[0]; bb[5] = (__bf16)hi[1];
            bb[6] = (__bf16)hi[2]; bb[7] = (__bf16)hi[3];
            b[j] = bb;
        }
#pragma unroll
        for (int i = 0; i < 4; i++)
#pragma unroll
            for (int j = 0; j < NJ; j++)
                acc[i][j] = __builtin_amdgcn_mfma_f32_16x16x32_bf16(a[i], b[j], acc[i][j], 0, 0, 0);
        __syncthreads();      // all reads of buf[s] done before next overwrite cycle
    }

    // D layout: row = q*4 + reg, col = lane&15 within each 16x16 tile
    if (EPI == 1) {
#pragma unroll
        for (int i = 0; i < 4; i++) {
            long rowb = m0 + mw + i * 16 + q * 4;
#pragma unroll
            for (int j = 0; j < NJ; j++) {
                int n = n0 + nw + j * 16 + r;
#pragma unroll
                for (int reg = 0; reg < 4; reg++) {
                    float v = acc[i][j][reg];
                    float o = __shfl_xor(v, 1);
                    if (!(r & 1)) {
                        float g = v, u = o;
                        float s2 = g / (1.f + __expf(-g)) * u;
                        Cbf[(rowb + reg) * (long)FF + (n >> 1)] = f2bf(s2);
                    }
                }
            }
        }
    } else {
#pragma unroll
        for (int i = 0; i < 4; i++) {
            long rowb = m0 + mw + i * 16 + q * 4;
#pragma unroll
            for (int j = 0; j < NJ; j++) {
                int n = n0 + nw + j * 16 + r;
#pragma unroll
                for (int reg = 0; reg < 4; reg++)
                    Cbf[(rowb + reg) * (long)HID + n] = f2bf(acc[i][j][reg]);
            }
        }
    }
}

// ---------------- weighted combine ----------------
__global__ void combine_kernel(const unsigned short* __restrict__ y,
                               const float* __restrict__ tw,
                               const int* __restrict__ pair_pos,
                               float* __restrict__ out) {
    int t = blockIdx.x;
    int c = threadIdx.x * 4;
    int p0 = pair_pos[t * 2], p1 = pair_pos[t * 2 + 1];
    float w0 = tw[t * 2], w1 = tw[t * 2 + 1];
    ushort4 a = *(const ushort4*)(y + (long)p0 * HID + c);
    ushort4 b = *(const ushort4*)(y + (long)p1 * HID + c);
    float4 o;
    o.x = w0 * bf2f(a.x) + w1 * bf2f(b.x);
    o.y = w0 * bf2f(a.y) + w1 * bf2f(b.y);
    o.z = w0 * bf2f(a.z) + w1 * bf2f(b.z);
    o.w = w0 * bf2f(a.w) + w1 * bf2f(b.w);
    *(float4*)(out + (long)t * HID + c) = o;
}

extern "C" void kernel_launch(void* const* d_in, const int* in_sizes, int n_in,
                              void* d_out, int out_size, void* d_ws, size_t ws_size,
                              hipStream_t stream) {
    const float* hs  = (const float*)d_in[0];
    const float* tw  = (const float*)d_in[1];
    const int*   ids = (const int*)d_in[2];
    const float* wgu = (const float*)d_in[3];
    const float* wdn = (const float*)d_in[4];
    float* out = (float*)d_out;

    char* ws = (char*)d_ws;
    size_t off = 0;
    auto alloc = [&](size_t bytes) -> void* {
        void* p = ws + off;
        off += (bytes + 255) & ~(size_t)255;
        return p;
    };
    unsigned short* hs_b  = (unsigned short*)alloc((size_t)T_TOK * HID * 2);    // 4 MB
    unsigned short* act   = (unsigned short*)alloc((size_t)MAXROWS * FF * 2);   // 10 MB
    unsigned short* ybuf  = (unsigned short*)alloc((size_t)MAXROWS * HID * 2);  // 10 MB
    int* pair_pos = (int*)alloc(NPAIR * 4);
    int* row_tok  = (int*)alloc(MAXROWS * 4);
    int* meta     = (int*)alloc(64);

    prep_kernel<<<257, 256, 0, stream>>>(hs, ids, pair_pos, row_tok, meta, hs_b);

    // GEMM1: (rows x 1024) x wgu_e(2048 x 1024)^T -> fused silu -> act (rows x 1024)
    gemm_moe<1, 16, 128><<<16 * MAX_MT, 256, 0, stream>>>(
        hs_b, wgu, act, meta, row_tok, HID, (long)(2 * FF) * HID);

    // GEMM2: (rows x 1024) x wdn_e(1024 x 1024)^T -> ybuf (rows x 1024) bf16
    gemm_moe<2, 8, 128><<<8 * MAX_MT, 256, 0, stream>>>(
        act, wdn, ybuf, meta, row_tok, FF, (long)HID * FF);

    combine_kernel<<<T_TOK, 256, 0, stream>>>(ybuf, tw, pair_pos, out);
}

// Round 9
// 209.313 us; speedup vs baseline: 1.1487x; 1.0432x over previous
//
#include <hip/hip_runtime.h>
#include <hip/hip_bf16.h>

// ---- problem constants ----
#define T_TOK 2048
#define HID   1024
#define FF    1024
#define NEXP  8
#define NPAIR 4096

// ---- GEMM tiling ----
#define BM 128
#define BK 32
#define MAX_MT 40
#define MAXROWS (MAX_MT*BM)   // 5120
#define PPT (NPAIR/256)       // 16

using bf16x8 = __attribute__((ext_vector_type(8))) __bf16;
using f32x4  = __attribute__((ext_vector_type(4))) float;
using us8    = __attribute__((ext_vector_type(8))) unsigned short;

__device__ __forceinline__ unsigned short f2bf(float f) {
    unsigned int u = __float_as_uint(f);
    return (unsigned short)((u + 0x7FFF + ((u >> 16) & 1)) >> 16);   // RNE
}
__device__ __forceinline__ float bf2f(unsigned short s) {
    return __uint_as_float(((unsigned int)s) << 16);
}
__device__ __forceinline__ void gll16(const unsigned short* g, unsigned short* l) {
    __builtin_amdgcn_global_load_lds(
        (const __attribute__((address_space(1))) void*)(const void*)g,
        (__attribute__((address_space(3))) void*)(void*)l, 16, 0, 0);
}
__device__ __forceinline__ ushort4 cvt4(float4 v) {
    ushort4 o; o.x = f2bf(v.x); o.y = f2bf(v.y); o.z = f2bf(v.z); o.w = f2bf(v.w);
    return o;
}

// ---------------- prep: loop-free streaming convert (16B stores) + scan ----------------
// Best measured prep (R4/R5 form, ~48 us): exact-sized grid, 8 independent
// float4 loads -> 4 us8 (16B) stores per thread, no loop bookkeeping.
//   [0,2048)      : wgu  (4.19M float4)
//   [2048,3072)   : wdn  (2.10M float4)
//   [3072,3328)   : hs   (0.52M float4)
//   3328          : expert-bucket prefix scan
#define B_WGU 2048
#define B_WDN 1024
#define B_HS  256
#define B_TOT (B_WGU + B_WDN + B_HS)   // 3328

__global__ void prep_kernel(const float* __restrict__ wgu,
                            const float* __restrict__ wdn,
                            const float* __restrict__ hs,
                            const int* __restrict__ ids,
                            int* __restrict__ pair_pos,
                            int* __restrict__ row_tok,
                            int* __restrict__ meta,
                            unsigned short* __restrict__ wgu_b,
                            unsigned short* __restrict__ wdn_b,
                            unsigned short* __restrict__ hs_b) {
    int tid = threadIdx.x;
    int bid = blockIdx.x;
    if (bid < B_TOT) {
        const float4* src;
        us8* dst;
        long rel;
        if (bid < B_WGU)            { src = (const float4*)wgu; dst = (us8*)wgu_b; rel = bid; }
        else if (bid < B_WGU+B_WDN) { src = (const float4*)wdn; dst = (us8*)wdn_b; rel = bid - B_WGU; }
        else                        { src = (const float4*)hs;  dst = (us8*)hs_b;  rel = bid - B_WGU - B_WDN; }
        long f4 = rel * 2048 + tid * 2;
        float4 v[8];
#pragma unroll
        for (int k = 0; k < 4; k++) {
            v[2 * k]     = src[f4 + k * 512];
            v[2 * k + 1] = src[f4 + k * 512 + 1];
        }
        long u8i = rel * 1024 + tid;
#pragma unroll
        for (int k = 0; k < 4; k++) {
            ushort4 lo = cvt4(v[2 * k]), hi = cvt4(v[2 * k + 1]);
            us8 o;
            o[0] = lo.x; o[1] = lo.y; o[2] = lo.z; o[3] = lo.w;
            o[4] = hi.x; o[5] = hi.y; o[6] = hi.z; o[7] = hi.w;
            dst[u8i + k * 256] = o;
        }
        return;
    }
    // ---- setup: bucket pairs by expert via prefix scan (no atomics) ----
    __shared__ int S[2][256][NEXP];
    __shared__ int base[NEXP];
    int myc[NEXP];
    int eloc[PPT];
#pragma unroll
    for (int e = 0; e < NEXP; e++) myc[e] = 0;
#pragma unroll
    for (int i = 0; i < PPT; i++) {
        int e = ids[tid * PPT + i];
        eloc[i] = e;
#pragma unroll
        for (int ee = 0; ee < NEXP; ee++) myc[ee] += (e == ee);
    }
#pragma unroll
    for (int e = 0; e < NEXP; e++) S[0][tid][e] = myc[e];
    __syncthreads();
    int src = 0;
    for (int d = 1; d < 256; d <<= 1) {
#pragma unroll
        for (int e = 0; e < NEXP; e++) {
            int v = S[src][tid][e];
            if (tid >= d) v += S[src][tid - d][e];
            S[src ^ 1][tid][e] = v;
        }
        __syncthreads();
        src ^= 1;
    }
    if (tid == 0) {
        int mt = 0;
        for (int e = 0; e < NEXP; e++) {
            meta[e] = mt;
            base[e] = mt * BM;
            mt += (S[src][255][e] + BM - 1) / BM;
        }
        meta[NEXP] = mt;
    }
    for (int i = tid; i < MAXROWS; i += 256) row_tok[i] = -1;
    __syncthreads();
    int off[NEXP];
#pragma unroll
    for (int e = 0; e < NEXP; e++) off[e] = base[e] + S[src][tid][e] - myc[e];
#pragma unroll
    for (int i = 0; i < PPT; i++) {
        int p = tid * PPT + i;
        int e = eloc[i];
        int pos = 0;
#pragma unroll
        for (int ee = 0; ee < NEXP; ee++) if (e == ee) pos = off[ee]++;
        pair_pos[p] = pos;
        row_tok[pos] = p >> 1;
    }
}

// ---------------- grouped GEMM, XCD-swizzled 1-D grid, gll16 dbuf ----------------
// Best measured GEMM structure (R1 form): BM=128, BN=128, all-bf16 operands,
// global_load_lds staging, simple 2-barrier double buffer, zero bank conflicts.
// Structural rewrites (counted vmcnt R5, split-K R7, fused fp32-B R2/R6/R8)
// all measured neutral-to-worse; this is the empirical optimum for this shape.
// EPI==1: A rows indirect via row_tok (clamped); B = wgu_b with gate/up
//         de-interleave in staging; epilogue silu(gate)*up -> bf16 act (FF cols).
// EPI==2: A = act (bucket-ordered, direct); epilogue plain bf16 store to ybuf.
template<int EPI, int NBY, int BN>
__global__ __launch_bounds__(256)
void gemm_moe(const unsigned short* __restrict__ A,
              const unsigned short* __restrict__ B,
              unsigned short* __restrict__ Cbf,
              const int* __restrict__ meta,
              const int* __restrict__ row_tok,
              int K, long Bexp) {
    constexpr int NJ = BN / 32;                    // 16-col MFMA tiles per wave
    constexpr int NBCH = (BN * BK) / (8 * 256);    // B 16B-chunks per thread
    __shared__ unsigned short As[2][BM * BK];      // 16 KB
    __shared__ unsigned short Bs[2][BN * BK];      // 16 KB @ BN=128

    // XCD-locality decode: xcd = L%8 gets NBY/8 consecutive by-slabs for ALL bx
    int L = blockIdx.x;
    int xcd = L & 7;
    int slot = L >> 3;
    constexpr int PER = NBY / 8;
    int by = xcd * PER + (slot % PER);
    int bx = slot / PER;
    if (bx >= meta[NEXP]) return;
    int e = 0;
#pragma unroll
    for (int i = 1; i < NEXP; i++) if (bx >= meta[i]) e = i;

    long m0 = (long)bx * BM;
    int n0 = by * BN;
    const unsigned short* Bb = B + (long)e * Bexp;

    int tid = threadIdx.x, lane = tid & 63, wv = tid >> 6;
    const int r = lane & 15;
    const int q = lane >> 4;
    const int mw = (wv >> 1) * 64, nw = (wv & 1) * (BN / 2);
    const int sw = (q ^ ((r >> 1) & 3)) * 8;

    // per-thread staging pointers (rows fixed across K)
    const unsigned short* ap[2];
#pragma unroll
    for (int h = 0; h < 2; h++) {
        int c = h * 256 + tid;
        int row = c >> 2, cp = c & 3;
        int cc = cp ^ ((row >> 1) & 3);
        long grow;
        if (EPI == 1) {
            int tk = row_tok[m0 + row];
            if (tk < 0) tk = 0;               // pad rows: finite garbage, never read
            grow = tk;
        } else {
            grow = m0 + row;
        }
        ap[h] = A + grow * (long)K + cc * 8;
    }
    const unsigned short* bp[NBCH];
#pragma unroll
    for (int h = 0; h < NBCH; h++) {
        int c = h * 256 + tid;
        int row = c >> 2, cp = c & 3;
        int cc = cp ^ ((row >> 1) & 3);
        long grow;
        if (EPI == 1) grow = ((row & 1) ? FF : 0) + ((n0 + row) >> 1);
        else          grow = n0 + row;
        bp[h] = Bb + grow * (long)K + cc * 8;
    }

    auto stage = [&](int s, int k0) {
#pragma unroll
        for (int h = 0; h < 2; h++)
            gll16(ap[h] + k0, &As[s][(h * 256 + tid) * 8]);
#pragma unroll
        for (int h = 0; h < NBCH; h++)
            gll16(bp[h] + k0, &Bs[s][(h * 256 + tid) * 8]);
    };

    f32x4 acc[4][NJ] = {};
    const int NKI = K / BK;   // 32
    stage(0, 0);
    for (int ki = 0; ki < NKI; ki++) {
        __syncthreads();      // buf[ki&1] loads landed; buf[(ki+1)&1] free to overwrite
        if (ki + 1 < NKI) stage((ki + 1) & 1, (ki + 1) * BK);
        int s = ki & 1;
        bf16x8 a[4], b[NJ];
#pragma unroll
        for (int i = 0; i < 4; i++)
            a[i] = *(const bf16x8*)&As[s][(mw + i * 16 + r) * BK + sw];
#pragma unroll
        for (int j = 0; j < NJ; j++)
            b[j] = *(const bf16x8*)&Bs[s][(nw + j * 16 + r) * BK + sw];
#pragma unroll
        for (int i = 0; i < 4; i++)
#pragma unroll
            for (int j = 0; j < NJ; j++)
                acc[i][j] = __builtin_amdgcn_mfma_f32_16x16x32_bf16(a[i], b[j], acc[i][j], 0, 0, 0);
        __syncthreads();      // all reads of buf[s] done before next overwrite cycle
    }

    // D layout: row = q*4 + reg, col = lane&15 within each 16x16 tile
    if (EPI == 1) {
#pragma unroll
        for (int i = 0; i < 4; i++) {
            long rowb = m0 + mw + i * 16 + q * 4;
#pragma unroll
            for (int j = 0; j < NJ; j++) {
                int n = n0 + nw + j * 16 + r;
#pragma unroll
                for (int reg = 0; reg < 4; reg++) {
                    float v = acc[i][j][reg];
                    float o = __shfl_xor(v, 1);
                    if (!(r & 1)) {
                        float g = v, u = o;
                        float s2 = g / (1.f + __expf(-g)) * u;
                        Cbf[(rowb + reg) * (long)FF + (n >> 1)] = f2bf(s2);
                    }
                }
            }
        }
    } else {
#pragma unroll
        for (int i = 0; i < 4; i++) {
            long rowb = m0 + mw + i * 16 + q * 4;
#pragma unroll
            for (int j = 0; j < NJ; j++) {
                int n = n0 + nw + j * 16 + r;
#pragma unroll
                for (int reg = 0; reg < 4; reg++)
                    Cbf[(rowb + reg) * (long)HID + n] = f2bf(acc[i][j][reg]);
            }
        }
    }
}

// ---------------- weighted combine ----------------
__global__ void combine_kernel(const unsigned short* __restrict__ y,
                               const float* __restrict__ tw,
                               const int* __restrict__ pair_pos,
                               float* __restrict__ out) {
    int t = blockIdx.x;
    int c = threadIdx.x * 4;
    int p0 = pair_pos[t * 2], p1 = pair_pos[t * 2 + 1];
    float w0 = tw[t * 2], w1 = tw[t * 2 + 1];
    ushort4 a = *(const ushort4*)(y + (long)p0 * HID + c);
    ushort4 b = *(const ushort4*)(y + (long)p1 * HID + c);
    float4 o;
    o.x = w0 * bf2f(a.x) + w1 * bf2f(b.x);
    o.y = w0 * bf2f(a.y) + w1 * bf2f(b.y);
    o.z = w0 * bf2f(a.z) + w1 * bf2f(b.z);
    o.w = w0 * bf2f(a.w) + w1 * bf2f(b.w);
    *(float4*)(out + (long)t * HID + c) = o;
}

extern "C" void kernel_launch(void* const* d_in, const int* in_sizes, int n_in,
                              void* d_out, int out_size, void* d_ws, size_t ws_size,
                              hipStream_t stream) {
    const float* hs  = (const float*)d_in[0];
    const float* tw  = (const float*)d_in[1];
    const int*   ids = (const int*)d_in[2];
    const float* wgu = (const float*)d_in[3];
    const float* wdn = (const float*)d_in[4];
    float* out = (float*)d_out;

    char* ws = (char*)d_ws;
    size_t off = 0;
    auto alloc = [&](size_t bytes) -> void* {
        void* p = ws + off;
        off += (bytes + 255) & ~(size_t)255;
        return p;
    };
    unsigned short* wgu_b = (unsigned short*)alloc((size_t)NEXP * 2 * FF * HID * 2); // 32 MB
    unsigned short* wdn_b = (unsigned short*)alloc((size_t)NEXP * HID * FF * 2);     // 16 MB
    unsigned short* hs_b  = (unsigned short*)alloc((size_t)T_TOK * HID * 2);         // 4 MB
    unsigned short* act   = (unsigned short*)alloc((size_t)MAXROWS * FF * 2);        // 10 MB
    unsigned short* ybuf  = (unsigned short*)alloc((size_t)MAXROWS * HID * 2);       // 10 MB
    int* pair_pos = (int*)alloc(NPAIR * 4);
    int* row_tok  = (int*)alloc(MAXROWS * 4);
    int* meta     = (int*)alloc(64);

    prep_kernel<<<B_TOT + 1, 256, 0, stream>>>(wgu, wdn, hs, ids,
                                               pair_pos, row_tok, meta,
                                               wgu_b, wdn_b, hs_b);

    // GEMM1: (rows x 1024) x B_e(2048 x 1024)^T -> fused silu -> act (rows x 1024)
    gemm_moe<1, 16, 128><<<16 * MAX_MT, 256, 0, stream>>>(
        hs_b, wgu_b, act, meta, row_tok, HID, (long)(2 * FF) * HID);

    // GEMM2: (rows x 1024) x B_e(1024 x 1024)^T -> ybuf (rows x 1024) bf16
    gemm_moe<2, 8, 128><<<8 * MAX_MT, 256, 0, stream>>>(
        act, wdn_b, ybuf, meta, row_tok, FF, (long)HID * FF);

    combine_kernel<<<T_TOK, 256, 0, stream>>>(ybuf, tw, pair_pos, out);
}